// Round 2
// baseline (622.211 us; speedup 1.0000x reference)
//
#include <hip/hip_runtime.h>
#include <math.h>

// AdaBoost fused inference, v3: branch-free fully-pipelined streaming MFMA.
//   logits = x @ W^T + b   [N=131072, E=256], F=512; pred = (logit > 0)
//   out = sign( sum_e trunc(alpha_e) * pred_e ), only cols with trunc(alpha)!=0 matter.
//
// Changes vs v2 (307 us/dispatch, latency-bound: runtime-NT branches forced
// load->vmcnt(0)->MFMA serialization; W fragment loads scattered over 16 lines):
//   - NT fixed at 8 (always 128 padded cols/pass; pad slots have st=0 -> no vote,
//     fragments come from W[0] -> finite). K-loop is 100% branch-free.
//   - Pre-kernel writes W hi/lo in MFMA *fragment order*: per (tile,kstep) a
//     contiguous 64-lane x 16B chunk -> every B-fragment load is one coalesced
//     1 KB global_load_dwordx4 (L2-resident).
//   - Explicit k-step register double-buffer (static idx via unrolled ks loop):
//     all 20 loads of step k+1 issue before step k's MFMAs -> counted vmcnt,
//     full k-step of latency cover per load. No LDS/barriers in hot loop.
//
// Numerics identical: fp32 -> bf16 split (RNE), 3-MFMA (xh*wh + xl*wh + xh*wl),
// |logit| < TAU re-decided with exact fp64 dot.

#define F_DIM  512
#define BM     128      // rows per block (4 waves x 32 rows)
#define BK     32       // k per MFMA step
#define KSTEPS 16       // F_DIM / BK
#define NT     8        // 16-col MFMA tiles per pass (always 128 cols)
#define WSLOTS 256
#define TAU    1e-3f

typedef float f32x4  __attribute__((ext_vector_type(4)));
typedef short bf16x8 __attribute__((ext_vector_type(8)));
typedef unsigned short u16x4 __attribute__((ext_vector_type(4)));

__device__ inline unsigned short bf16_rne(float v) {
    unsigned u = __float_as_uint(v);
    u += 0x7FFFu + ((u >> 16) & 1u);
    return (unsigned short)(u >> 16);
}
__device__ inline float bf16_to_f32(unsigned short h) {
    return __uint_as_float(((unsigned)h) << 16);
}

// split 8 floats (a[0..3], b[0..3]) into bf16 hi/lo fragments
__device__ inline void cvt8(const f32x4 a, const f32x4 b, bf16x8& hi, bf16x8& lo) {
    #pragma unroll
    for (int j = 0; j < 4; ++j) {
        const float v0 = a[j], v1 = b[j];
        const unsigned short h0 = bf16_rne(v0);
        const unsigned short h1 = bf16_rne(v1);
        hi[j]     = (short)h0;
        hi[j + 4] = (short)h1;
        lo[j]     = (short)bf16_rne(v0 - bf16_to_f32(h0));
        lo[j + 4] = (short)bf16_rne(v1 - bf16_to_f32(h1));
    }
}

__device__ __attribute__((noinline)) bool exact_pred(const float* __restrict__ xr,
                                                     const float* __restrict__ wr,
                                                     float bv) {
    double s0 = 0.0, s1 = 0.0, s2 = 0.0, s3 = 0.0;
    for (int k = 0; k < F_DIM; k += 4) {
        s0 = fma((double)xr[k + 0], (double)wr[k + 0], s0);
        s1 = fma((double)xr[k + 1], (double)wr[k + 1], s1);
        s2 = fma((double)xr[k + 2], (double)wr[k + 2], s2);
        s3 = fma((double)xr[k + 3], (double)wr[k + 3], s3);
    }
    double s = ((s0 + s1) + (s2 + s3)) + (double)bv;
    return s > 0.0;
}

// ---------------- pre-kernel: compact active estimators, split W -> bf16 hi/lo
// fragments in ws, laid out in MFMA fragment order:
//   frag[((tile*16 + ks)*64 + lane)*8 + j] = bf16(W[se[tile*16 + (lane&15)]]
//                                                  [ks*32 + (lane>>4)*8 + j])
// so a wave's B-fragment load for (tile,ks) is one contiguous 1 KB chunk.
__global__ __launch_bounds__(256)
void ada_prep(const float* __restrict__ W, const float* __restrict__ alphas,
              unsigned short* __restrict__ whi, unsigned short* __restrict__ wlo) {
    __shared__ int se[WSLOTS];
    __shared__ int wcnt[4];
    const int tid = threadIdx.x;

    se[tid] = 0;
    __syncthreads();
    const float t = truncf(alphas[tid]);
    const bool flag = (t != 0.0f);
    const unsigned long long m64 = __ballot(flag);
    const int lane = tid & 63, wvi = tid >> 6;
    if (lane == 0) wcnt[wvi] = __popcll(m64);
    __syncthreads();
    int off = 0;
    #pragma unroll
    for (int w = 0; w < 4; ++w) if (w < wvi) off += wcnt[w];
    if (flag) se[off + __popcll(m64 & ((1ull << lane) - 1ull))] = tid;
    __syncthreads();

    // 16384 jobs total = 64 blocks x 256 threads; one job = 8 elements
    const int job  = blockIdx.x * 256 + tid;
    const int slot = job >> 6;          // 0..255 (column)
    const int rem  = job & 63;
    const int ks   = rem >> 2;          // 0..15
    const int quad = rem & 3;           // 0..3
    const int tile = slot >> 4;
    const int l15  = slot & 15;

    const float* src = W + (size_t)se[slot] * F_DIM + ks * 32 + quad * 8;
    const f32x4 a = *(const f32x4*)(src);
    const f32x4 b = *(const f32x4*)(src + 4);
    bf16x8 hi, lo;
    cvt8(a, b, hi, lo);

    const size_t dst = ((size_t)(tile * 16 + ks) * 64 + (quad * 16 + l15)) * 8;
    *(bf16x8*)(whi + dst) = hi;
    *(bf16x8*)(wlo + dst) = lo;
}

// ---------------- main kernel: barrier-free, branch-free streaming GEMM + vote
__global__ __launch_bounds__(256, 2)
void ada_mfma3(const float* __restrict__ x, const float* __restrict__ W,
               const float* __restrict__ bias, const float* __restrict__ alphas,
               const unsigned short* __restrict__ whi, const unsigned short* __restrict__ wlo,
               float* __restrict__ out) {
    __shared__ int   se[WSLOTS];
    __shared__ float st[WSLOTS];
    __shared__ float sb[WSLOTS];
    __shared__ int   wcnt[4];

    const int tid = threadIdx.x;
    const int n0  = blockIdx.x * BM;

    // ---- compaction of active estimators (deterministic ballot prefix-sum)
    se[tid] = 0; st[tid] = 0.0f; sb[tid] = 0.0f;
    __syncthreads();
    const float t = truncf(alphas[tid]);
    const bool flag = (t != 0.0f);
    const unsigned long long m64 = __ballot(flag);
    const int lane = tid & 63, wvi = tid >> 6;
    if (lane == 0) wcnt[wvi] = __popcll(m64);
    __syncthreads();
    int off = 0;
    #pragma unroll
    for (int w = 0; w < 4; ++w) if (w < wvi) off += wcnt[w];
    const int M = wcnt[0] + wcnt[1] + wcnt[2] + wcnt[3];
    if (flag) {
        const int slot = off + __popcll(m64 & ((1ull << lane) - 1ull));
        se[slot] = tid; st[slot] = t; sb[slot] = bias[tid];
    }
    __syncthreads();   // last barrier in the kernel

    // ---- ids
    const int quad = (tid >> 4) & 3;    // lane>>4 within wave
    const int l15  = tid & 15;
    const int rw   = (tid >> 6) * 32;   // wave's row base within block

    // per-lane x row pointers (mt=0/1), already offset by quad*8 in k
    const float* xp0 = x + (size_t)(n0 + rw + l15) * F_DIM + quad * 8;
    const float* xp1 = xp0 + (size_t)16 * F_DIM;

    // per-lane W fragment base (fragment-order layout)
    const unsigned short* wbh_base = whi + (size_t)lane * 8;
    const unsigned short* wbl_base = wlo + (size_t)lane * 8;

    int part[2][4];
    #pragma unroll
    for (int mt = 0; mt < 2; ++mt)
        #pragma unroll
        for (int r = 0; r < 4; ++r) part[mt][r] = 0;

    for (int cb = 0; cb < M; cb += 128) {
        const int p8 = cb >> 4;         // tile base (0 or 8)

        f32x4 acc[2][NT];
        #pragma unroll
        for (int mt = 0; mt < 2; ++mt)
            #pragma unroll
            for (int nt = 0; nt < NT; ++nt)
                acc[mt][nt] = (f32x4){0.0f, 0.0f, 0.0f, 0.0f};

        // double-buffered register pipeline (static idx: ks loop fully unrolled)
        f32x4  xv[2][4];
        bf16x8 wh[2][NT], wl[2][NT];

        // prologue: loads for ks = 0
        xv[0][0] = *(const f32x4*)(xp0);
        xv[0][1] = *(const f32x4*)(xp0 + 4);
        xv[0][2] = *(const f32x4*)(xp1);
        xv[0][3] = *(const f32x4*)(xp1 + 4);
        #pragma unroll
        for (int nt = 0; nt < NT; ++nt) {
            const size_t o = (size_t)((p8 + nt) * 16) * 512;   // shorts
            wh[0][nt] = *(const bf16x8*)(wbh_base + o);
            wl[0][nt] = *(const bf16x8*)(wbl_base + o);
        }

        #pragma unroll
        for (int ks = 0; ks < KSTEPS; ++ks) {
            const int cur = ks & 1, nxt = cur ^ 1;

            // issue ALL loads for ks+1 first (independent of everything below)
            if (ks + 1 < KSTEPS) {
                const int kf = (ks + 1) * BK;
                xv[nxt][0] = *(const f32x4*)(xp0 + kf);
                xv[nxt][1] = *(const f32x4*)(xp0 + kf + 4);
                xv[nxt][2] = *(const f32x4*)(xp1 + kf);
                xv[nxt][3] = *(const f32x4*)(xp1 + kf + 4);
                #pragma unroll
                for (int nt = 0; nt < NT; ++nt) {
                    const size_t o = (size_t)((p8 + nt) * 16 + ks + 1) * 512;
                    wh[nxt][nt] = *(const bf16x8*)(wbh_base + o);
                    wl[nxt][nt] = *(const bf16x8*)(wbl_base + o);
                }
            }

            // convert current x fragments to bf16 hi/lo in registers
            bf16x8 ah0, al0, ah1, al1;
            cvt8(xv[cur][0], xv[cur][1], ah0, al0);
            cvt8(xv[cur][2], xv[cur][3], ah1, al1);

            // 48 MFMAs, mt-interleaved for dependency spacing
            #pragma unroll
            for (int nt = 0; nt < NT; ++nt) {
                acc[0][nt] = __builtin_amdgcn_mfma_f32_16x16x32_bf16(ah0, wh[cur][nt], acc[0][nt], 0, 0, 0);
                acc[1][nt] = __builtin_amdgcn_mfma_f32_16x16x32_bf16(ah1, wh[cur][nt], acc[1][nt], 0, 0, 0);
                acc[0][nt] = __builtin_amdgcn_mfma_f32_16x16x32_bf16(al0, wh[cur][nt], acc[0][nt], 0, 0, 0);
                acc[1][nt] = __builtin_amdgcn_mfma_f32_16x16x32_bf16(al1, wh[cur][nt], acc[1][nt], 0, 0, 0);
                acc[0][nt] = __builtin_amdgcn_mfma_f32_16x16x32_bf16(ah0, wl[cur][nt], acc[0][nt], 0, 0, 0);
                acc[1][nt] = __builtin_amdgcn_mfma_f32_16x16x32_bf16(ah1, wl[cur][nt], acc[1][nt], 0, 0, 0);
            }
        }

        // ---- epilogue: threshold + integer vote (C/D: col=l15, row=quad*4+reg)
        #pragma unroll
        for (int nt = 0; nt < NT; ++nt) {
            const int col = cb + nt * 16 + l15;
            const float tv = st[col];
            if (tv != 0.0f) {
                const float bv = sb[col];
                const int it = (int)tv;
                #pragma unroll
                for (int mt = 0; mt < 2; ++mt) {
                    #pragma unroll
                    for (int r = 0; r < 4; ++r) {
                        const float logit = acc[mt][nt][r] + bv;
                        bool pred = (logit > 0.0f);
                        if (fabsf(logit) < TAU) {
                            const int row = rw + mt * 16 + quad * 4 + r;
                            pred = exact_pred(x + (size_t)(n0 + row) * F_DIM,
                                              W + (size_t)se[col] * F_DIM, bv);
                        }
                        if (pred) part[mt][r] += it;
                    }
                }
            }
        }
    }

    // ---- reduce the 16 col-lanes of each quad, then store 4 consecutive rows
    #pragma unroll
    for (int mt = 0; mt < 2; ++mt) {
        #pragma unroll
        for (int r = 0; r < 4; ++r) {
            int v = part[mt][r];
            v += __shfl_xor(v, 1);
            v += __shfl_xor(v, 2);
            v += __shfl_xor(v, 4);
            v += __shfl_xor(v, 8);
            part[mt][r] = v;
        }
    }
    if (l15 == 0) {
        #pragma unroll
        for (int mt = 0; mt < 2; ++mt) {
            float4 o;
            o.x = (part[mt][0] > 0) ? 1.0f : (part[mt][0] < 0 ? -1.0f : 0.0f);
            o.y = (part[mt][1] > 0) ? 1.0f : (part[mt][1] < 0 ? -1.0f : 0.0f);
            o.z = (part[mt][2] > 0) ? 1.0f : (part[mt][2] < 0 ? -1.0f : 0.0f);
            o.w = (part[mt][3] > 0) ? 1.0f : (part[mt][3] < 0 ? -1.0f : 0.0f);
            *(float4*)(out + n0 + rw + mt * 16 + quad * 4) = o;
        }
    }
}

extern "C" void kernel_launch(void* const* d_in, const int* in_sizes, int n_in,
                              void* d_out, int out_size, void* d_ws, size_t ws_size,
                              hipStream_t stream) {
    const float* x      = (const float*)d_in[0];   // [N, 512]
    const float* W      = (const float*)d_in[1];   // [256, 512]
    const float* bias   = (const float*)d_in[2];   // [256]
    const float* alphas = (const float*)d_in[3];   // [256]
    float* out = (float*)d_out;                    // [N]

    const int n = in_sizes[0] / F_DIM;             // 131072
    const int nblocks = n / BM;                    // 1024

    // ws: whi [256*512] ushort, wlo [256*512] ushort (fragment order, 512 KB)
    unsigned short* whi = (unsigned short*)d_ws;
    unsigned short* wlo = whi + (size_t)WSLOTS * F_DIM;

    ada_prep<<<dim3(64), dim3(256), 0, stream>>>(W, alphas, whi, wlo);
    ada_mfma3<<<dim3(nblocks), dim3(256), 0, stream>>>(x, W, bias, alphas, whi, wlo, out);
}

// Round 3
// 549.738 us; speedup vs baseline: 1.1318x; 1.1318x over previous
//
#include <hip/hip_runtime.h>
#include <math.h>

// AdaBoost fused inference, v4: m97-style LDS-staged W + register-streamed x.
//   logits = x @ W^T + b   [N=131072, E=256], F=512; pred = (logit > 0)
//   out = sign( sum_e trunc(alpha_e) * pred_e ), only cols with trunc(alpha)!=0 matter.
//
// v3 post-mortem: W-fragment register double-buffer (128 VGPRs) spilled to
// scratch -> WRITE_SIZE 168 MB, 432 us. Fix: W fragments belong in LDS.
//   - W: pre-converted ONCE (prep kernel) to bf16 hi/lo in fragment-linear
//     order; staged per k-step via global_load_lds width=16 (DMA, no VGPRs,
//     linear dest = wave-uniform base + lane*16), double-buffered 2x16 KB.
//     4x cross-wave reuse from LDS; source stays L2-resident (512 KB).
//   - x: zero cross-wave reuse -> per-lane float4 direct to regs, issued one
//     k-step ahead; bf16 hi/lo split at use. No LDS, no conflicts.
//   - One __syncthreads per k-step (m97 pattern); k-loop fully unrolled,
//     branch-free, NT=8 compile-time (pad cols have st=0 -> no vote).
//
// Numerics identical: fp32 -> bf16 split (RNE), 3-MFMA (xh*wh + xl*wh + xh*wl),
// |logit| < TAU re-decided with exact fp64 dot.

#define F_DIM  512
#define BM     128      // rows per block (4 waves x 32 rows)
#define BK     32       // k per MFMA step
#define KSTEPS 16       // F_DIM / BK
#define NT     8        // 16-col MFMA tiles per pass (always 128 cols)
#define WSLOTS 256
#define TAU    1e-3f

typedef float f32x4  __attribute__((ext_vector_type(4)));
typedef short bf16x8 __attribute__((ext_vector_type(8)));

__device__ inline unsigned short bf16_rne(float v) {
    unsigned u = __float_as_uint(v);
    u += 0x7FFFu + ((u >> 16) & 1u);
    return (unsigned short)(u >> 16);
}
__device__ inline float bf16_to_f32(unsigned short h) {
    return __uint_as_float(((unsigned)h) << 16);
}

// split 8 floats (a[0..3], b[0..3]) into bf16 hi/lo fragments
__device__ inline void cvt8(const f32x4 a, const f32x4 b, bf16x8& hi, bf16x8& lo) {
    #pragma unroll
    for (int j = 0; j < 4; ++j) {
        const float v0 = a[j], v1 = b[j];
        const unsigned short h0 = bf16_rne(v0);
        const unsigned short h1 = bf16_rne(v1);
        hi[j]     = (short)h0;
        hi[j + 4] = (short)h1;
        lo[j]     = (short)bf16_rne(v0 - bf16_to_f32(h0));
        lo[j + 4] = (short)bf16_rne(v1 - bf16_to_f32(h1));
    }
}

__device__ __attribute__((noinline)) bool exact_pred(const float* __restrict__ xr,
                                                     const float* __restrict__ wr,
                                                     float bv) {
    double s0 = 0.0, s1 = 0.0, s2 = 0.0, s3 = 0.0;
    for (int k = 0; k < F_DIM; k += 4) {
        s0 = fma((double)xr[k + 0], (double)wr[k + 0], s0);
        s1 = fma((double)xr[k + 1], (double)wr[k + 1], s1);
        s2 = fma((double)xr[k + 2], (double)wr[k + 2], s2);
        s3 = fma((double)xr[k + 3], (double)wr[k + 3], s3);
    }
    double s = ((s0 + s1) + (s2 + s3)) + (double)bv;
    return s > 0.0;
}

// ---------------- pre-kernel: compact active estimators, split W -> bf16 hi/lo
// fragments in ws, fragment-LINEAR layout (stage-able by global_load_lds):
//   wfrag[((((p*16 + ks)*8 + t8)*2 + c)*64 + lane)*8 + j]
//     = bf16_c( W[ se[p*128 + t8*16 + (lane&15)] ][ ks*32 + (lane>>4)*8 + j ] )
// One (p,ks) block = 16 KB, contiguous.
__global__ __launch_bounds__(256)
void ada_prep(const float* __restrict__ W, const float* __restrict__ alphas,
              unsigned short* __restrict__ wfrag) {
    __shared__ int se[WSLOTS];
    __shared__ int wcnt[4];
    const int tid = threadIdx.x;

    se[tid] = 0;
    __syncthreads();
    const float t = truncf(alphas[tid]);
    const bool flag = (t != 0.0f);
    const unsigned long long m64 = __ballot(flag);
    const int lane = tid & 63, wvi = tid >> 6;
    if (lane == 0) wcnt[wvi] = __popcll(m64);
    __syncthreads();
    int off = 0;
    #pragma unroll
    for (int w = 0; w < 4; ++w) if (w < wvi) off += wcnt[w];
    if (flag) se[off + __popcll(m64 & ((1ull << lane) - 1ull))] = tid;
    __syncthreads();

    // 16384 jobs = 64 blocks x 256 threads; one job = one 8-elem lane fragment
    const int job = blockIdx.x * 256 + tid;
    const int jl  = job & 63;            // dest lane
    const int t8  = (job >> 6) & 7;      // tile within pass
    const int ks  = (job >> 9) & 15;     // k-step
    const int p   = (job >> 13) & 1;     // pass
    const int col = p * 128 + t8 * 16 + (jl & 15);
    const int k   = ks * 32 + (jl >> 4) * 8;

    const float* src = W + (size_t)se[col] * F_DIM + k;
    const f32x4 a = *(const f32x4*)(src);
    const f32x4 b = *(const f32x4*)(src + 4);
    bf16x8 hi, lo;
    cvt8(a, b, hi, lo);

    const size_t base = ((((size_t)(p * 16 + ks) * 8 + t8) * 2 + 0) * 64 + jl) * 8;
    *(bf16x8*)(wfrag + base)       = hi;
    *(bf16x8*)(wfrag + base + 512) = lo;      // c=1 block is +64 lanes * 8 shorts
}

// ---------------- main kernel
__global__ __launch_bounds__(256, 2)
void ada_mfma4(const float* __restrict__ x, const float* __restrict__ W,
               const float* __restrict__ bias, const float* __restrict__ alphas,
               const unsigned short* __restrict__ wfrag,
               float* __restrict__ out) {
    __shared__ unsigned short wbuf[2][8192];   // 2 x 16 KB W-fragment k-step buffers
    __shared__ int   se[WSLOTS];
    __shared__ float st[WSLOTS];
    __shared__ float sb[WSLOTS];
    __shared__ int   wcnt[4];

    const int tid = threadIdx.x;
    const int n0  = blockIdx.x * BM;

    // ---- compaction of active estimators (deterministic ballot prefix-sum)
    se[tid] = 0; st[tid] = 0.0f; sb[tid] = 0.0f;
    __syncthreads();
    const float t = truncf(alphas[tid]);
    const bool flag = (t != 0.0f);
    const unsigned long long m64 = __ballot(flag);
    const int lane = tid & 63, wv = tid >> 6;
    if (lane == 0) wcnt[wv] = __popcll(m64);
    __syncthreads();
    int off = 0;
    #pragma unroll
    for (int w = 0; w < 4; ++w) if (w < wv) off += wcnt[w];
    const int M = wcnt[0] + wcnt[1] + wcnt[2] + wcnt[3];
    if (flag) {
        const int slot = off + __popcll(m64 & ((1ull << lane) - 1ull));
        se[slot] = tid; st[slot] = t; sb[slot] = bias[tid];
    }
    __syncthreads();

    // ---- ids
    const int quad = (tid >> 4) & 3;
    const int l15  = tid & 15;
    const int rw   = wv * 32;            // wave's row base within block

    const float* xp0 = x + (size_t)(n0 + rw + l15) * F_DIM + quad * 8;
    const float* xp1 = xp0 + (size_t)16 * F_DIM;

    int part[2][4];
    #pragma unroll
    for (int mt = 0; mt < 2; ++mt)
        #pragma unroll
        for (int r = 0; r < 4; ++r) part[mt][r] = 0;

    for (int cb = 0; cb < M; cb += 128) {
        const unsigned short* wsp = wfrag + (size_t)(cb >> 7) * KSTEPS * 8192;

        f32x4 acc[2][NT];
        #pragma unroll
        for (int mt = 0; mt < 2; ++mt)
            #pragma unroll
            for (int nt = 0; nt < NT; ++nt)
                acc[mt][nt] = (f32x4){0.0f, 0.0f, 0.0f, 0.0f};

        // prologue: stage W k-step 0 into buf0 (DMA), load x k-step 0 to regs
        {
            const unsigned short* gs = wsp + wv * 2048 + lane * 8;
            unsigned short* lb = &wbuf[0][wv * 2048];
            #pragma unroll
            for (int i = 0; i < 4; ++i)
                __builtin_amdgcn_global_load_lds(
                    (const __attribute__((address_space(1))) void*)(gs + i * 512),
                    (__attribute__((address_space(3))) void*)(lb + i * 512),
                    16, 0, 0);
        }
        f32x4 xv0 = *(const f32x4*)(xp0);
        f32x4 xv1 = *(const f32x4*)(xp0 + 4);
        f32x4 xv2 = *(const f32x4*)(xp1);
        f32x4 xv3 = *(const f32x4*)(xp1 + 4);
        __syncthreads();   // stage(0) + x(0) complete

        #pragma unroll
        for (int ks = 0; ks < KSTEPS; ++ks) {
            const int cur = ks & 1;

            // issue next k-step's W stage (DMA into other buffer) + x loads
            f32x4 xn0, xn1, xn2, xn3;
            if (ks + 1 < KSTEPS) {
                const unsigned short* gs = wsp + (size_t)(ks + 1) * 8192 + wv * 2048 + lane * 8;
                unsigned short* lb = &wbuf[cur ^ 1][wv * 2048];
                #pragma unroll
                for (int i = 0; i < 4; ++i)
                    __builtin_amdgcn_global_load_lds(
                        (const __attribute__((address_space(1))) void*)(gs + i * 512),
                        (__attribute__((address_space(3))) void*)(lb + i * 512),
                        16, 0, 0);
                const int kf = (ks + 1) * BK;
                xn0 = *(const f32x4*)(xp0 + kf);
                xn1 = *(const f32x4*)(xp0 + kf + 4);
                xn2 = *(const f32x4*)(xp1 + kf);
                xn3 = *(const f32x4*)(xp1 + kf + 4);
            }

            // convert current x to bf16 hi/lo in registers
            bf16x8 ah0, al0, ah1, al1;
            cvt8(xv0, xv1, ah0, al0);
            cvt8(xv2, xv3, ah1, al1);

            // 16 ds_read_b128 + 48 MFMAs from LDS buffer `cur`
            const unsigned short* wb = wbuf[cur];
            #pragma unroll
            for (int nt = 0; nt < NT; ++nt) {
                const bf16x8 bh = *(const bf16x8*)&wb[(nt * 2 + 0) * 512 + lane * 8];
                const bf16x8 bl = *(const bf16x8*)&wb[(nt * 2 + 1) * 512 + lane * 8];
                acc[0][nt] = __builtin_amdgcn_mfma_f32_16x16x32_bf16(ah0, bh, acc[0][nt], 0, 0, 0);
                acc[1][nt] = __builtin_amdgcn_mfma_f32_16x16x32_bf16(ah1, bh, acc[1][nt], 0, 0, 0);
                acc[0][nt] = __builtin_amdgcn_mfma_f32_16x16x32_bf16(al0, bh, acc[0][nt], 0, 0, 0);
                acc[1][nt] = __builtin_amdgcn_mfma_f32_16x16x32_bf16(al1, bh, acc[1][nt], 0, 0, 0);
                acc[0][nt] = __builtin_amdgcn_mfma_f32_16x16x32_bf16(ah0, bl, acc[0][nt], 0, 0, 0);
                acc[1][nt] = __builtin_amdgcn_mfma_f32_16x16x32_bf16(ah1, bl, acc[1][nt], 0, 0, 0);
            }

            __syncthreads();   // next buf staged (vmcnt drain) + cur reads done

            if (ks + 1 < KSTEPS) { xv0 = xn0; xv1 = xn1; xv2 = xn2; xv3 = xn3; }
        }

        // ---- epilogue: threshold + integer vote (C/D: col=l15, row=quad*4+reg)
        #pragma unroll
        for (int nt = 0; nt < NT; ++nt) {
            const int col = cb + nt * 16 + l15;
            const float tv = st[col];
            if (tv != 0.0f) {
                const float bv = sb[col];
                const int it = (int)tv;
                #pragma unroll
                for (int mt = 0; mt < 2; ++mt) {
                    #pragma unroll
                    for (int r = 0; r < 4; ++r) {
                        const float logit = acc[mt][nt][r] + bv;
                        bool pred = (logit > 0.0f);
                        if (fabsf(logit) < TAU) {
                            const int row = rw + mt * 16 + quad * 4 + r;
                            pred = exact_pred(x + (size_t)(n0 + row) * F_DIM,
                                              W + (size_t)se[col] * F_DIM, bv);
                        }
                        if (pred) part[mt][r] += it;
                    }
                }
            }
        }
    }

    // ---- reduce the 16 col-lanes of each quad, then store 4 consecutive rows
    #pragma unroll
    for (int mt = 0; mt < 2; ++mt) {
        #pragma unroll
        for (int r = 0; r < 4; ++r) {
            int v = part[mt][r];
            v += __shfl_xor(v, 1);
            v += __shfl_xor(v, 2);
            v += __shfl_xor(v, 4);
            v += __shfl_xor(v, 8);
            part[mt][r] = v;
        }
    }
    if (l15 == 0) {
        #pragma unroll
        for (int mt = 0; mt < 2; ++mt) {
            float4 o;
            o.x = (part[mt][0] > 0) ? 1.0f : (part[mt][0] < 0 ? -1.0f : 0.0f);
            o.y = (part[mt][1] > 0) ? 1.0f : (part[mt][1] < 0 ? -1.0f : 0.0f);
            o.z = (part[mt][2] > 0) ? 1.0f : (part[mt][2] < 0 ? -1.0f : 0.0f);
            o.w = (part[mt][3] > 0) ? 1.0f : (part[mt][3] < 0 ? -1.0f : 0.0f);
            *(float4*)(out + n0 + rw + mt * 16 + quad * 4) = o;
        }
    }
}

extern "C" void kernel_launch(void* const* d_in, const int* in_sizes, int n_in,
                              void* d_out, int out_size, void* d_ws, size_t ws_size,
                              hipStream_t stream) {
    const float* x      = (const float*)d_in[0];   // [N, 512]
    const float* W      = (const float*)d_in[1];   // [256, 512]
    const float* bias   = (const float*)d_in[2];   // [256]
    const float* alphas = (const float*)d_in[3];   // [256]
    float* out = (float*)d_out;                    // [N]

    const int n = in_sizes[0] / F_DIM;             // 131072
    const int nblocks = n / BM;                    // 1024

    // ws: W fragments bf16 hi/lo, fragment-linear, 2 passes x 16 ksteps x 16 KB = 512 KB
    unsigned short* wfrag = (unsigned short*)d_ws;

    ada_prep<<<dim3(64), dim3(256), 0, stream>>>(W, alphas, wfrag);
    ada_mfma4<<<dim3(nblocks), dim3(256), 0, stream>>>(x, W, bias, alphas, wfrag, out);
}

// Round 4
// 539.630 us; speedup vs baseline: 1.1530x; 1.0187x over previous
//
#include <hip/hip_runtime.h>
#include <math.h>

// AdaBoost fused inference, v5: v4 structure + call-free epilogue (spill fix).
//   logits = x @ W^T + b   [N=131072, E=256], F=512; pred = (logit > 0)
//   out = sign( sum_e trunc(alpha_e) * pred_e ), only cols with trunc(alpha)!=0 matter.
//
// v4 post-mortem: WRITE_SIZE 167 MB scratch traffic came from the EPILOGUE:
// exact_pred is a noinline CALL executed while all 64 acc VGPRs were live, so
// the allocator spilled acc around the call region -> scratch-bound k-loop.
// v5: two-phase epilogue. Phase 1 (call-free) folds acc into vote sums and two
// 64-bit masks (pred / borderline); acc is dead afterwards. Phase 2 (rare,
// ~4% of threads) walks the borderline mask with STATIC part[][] indexing and
// calls exact_pred with only a handful of scalars live.
// Also: x converted to bf16 hi/lo at k-step top (consumes prefetch regs early,
// -16 VGPRs steady state). K-loop identical to v4: W fragments pre-converted
// to bf16 hi/lo fragment-linear in ws, staged per k-step via global_load_lds
// width=16 (DMA, wave-uniform base + lane*16), double-buffered 2x16 KB; x
// per-lane float4 prefetch; one barrier per k-step; branch-free; NT=8.

#define F_DIM  512
#define BM     128      // rows per block (4 waves x 32 rows)
#define BK     32       // k per MFMA step
#define KSTEPS 16       // F_DIM / BK
#define NT     8        // 16-col MFMA tiles per pass (always 128 cols)
#define WSLOTS 256
#define TAU    1e-3f

typedef float f32x4  __attribute__((ext_vector_type(4)));
typedef short bf16x8 __attribute__((ext_vector_type(8)));

__device__ inline unsigned short bf16_rne(float v) {
    unsigned u = __float_as_uint(v);
    u += 0x7FFFu + ((u >> 16) & 1u);
    return (unsigned short)(u >> 16);
}
__device__ inline float bf16_to_f32(unsigned short h) {
    return __uint_as_float(((unsigned)h) << 16);
}

// split 8 floats (a[0..3], b[0..3]) into bf16 hi/lo fragments
__device__ inline void cvt8(const f32x4 a, const f32x4 b, bf16x8& hi, bf16x8& lo) {
    #pragma unroll
    for (int j = 0; j < 4; ++j) {
        const float v0 = a[j], v1 = b[j];
        const unsigned short h0 = bf16_rne(v0);
        const unsigned short h1 = bf16_rne(v1);
        hi[j]     = (short)h0;
        hi[j + 4] = (short)h1;
        lo[j]     = (short)bf16_rne(v0 - bf16_to_f32(h0));
        lo[j + 4] = (short)bf16_rne(v1 - bf16_to_f32(h1));
    }
}

__device__ __attribute__((noinline)) bool exact_pred(const float* __restrict__ xr,
                                                     const float* __restrict__ wr,
                                                     float bv) {
    double s0 = 0.0, s1 = 0.0, s2 = 0.0, s3 = 0.0;
    for (int k = 0; k < F_DIM; k += 4) {
        s0 = fma((double)xr[k + 0], (double)wr[k + 0], s0);
        s1 = fma((double)xr[k + 1], (double)wr[k + 1], s1);
        s2 = fma((double)xr[k + 2], (double)wr[k + 2], s2);
        s3 = fma((double)xr[k + 3], (double)wr[k + 3], s3);
    }
    double s = ((s0 + s1) + (s2 + s3)) + (double)bv;
    return s > 0.0;
}

// ---------------- pre-kernel: compact active estimators, split W -> bf16 hi/lo
// fragments in ws, fragment-LINEAR layout (stage-able by global_load_lds):
//   wfrag[((((p*16 + ks)*8 + t8)*2 + c)*64 + lane)*8 + j]
//     = bf16_c( W[ se[p*128 + t8*16 + (lane&15)] ][ ks*32 + (lane>>4)*8 + j ] )
// One (p,ks) block = 16 KB, contiguous.
__global__ __launch_bounds__(256)
void ada_prep(const float* __restrict__ W, const float* __restrict__ alphas,
              unsigned short* __restrict__ wfrag) {
    __shared__ int se[WSLOTS];
    __shared__ int wcnt[4];
    const int tid = threadIdx.x;

    se[tid] = 0;
    __syncthreads();
    const float t = truncf(alphas[tid]);
    const bool flag = (t != 0.0f);
    const unsigned long long m64 = __ballot(flag);
    const int lane = tid & 63, wvi = tid >> 6;
    if (lane == 0) wcnt[wvi] = __popcll(m64);
    __syncthreads();
    int off = 0;
    #pragma unroll
    for (int w = 0; w < 4; ++w) if (w < wvi) off += wcnt[w];
    if (flag) se[off + __popcll(m64 & ((1ull << lane) - 1ull))] = tid;
    __syncthreads();

    // 16384 jobs = 64 blocks x 256 threads; one job = one 8-elem lane fragment
    const int job = blockIdx.x * 256 + tid;
    const int jl  = job & 63;            // dest lane
    const int t8  = (job >> 6) & 7;      // tile within pass
    const int ks  = (job >> 9) & 15;     // k-step
    const int p   = (job >> 13) & 1;     // pass
    const int col = p * 128 + t8 * 16 + (jl & 15);
    const int k   = ks * 32 + (jl >> 4) * 8;

    const float* src = W + (size_t)se[col] * F_DIM + k;
    const f32x4 a = *(const f32x4*)(src);
    const f32x4 b = *(const f32x4*)(src + 4);
    bf16x8 hi, lo;
    cvt8(a, b, hi, lo);

    const size_t base = ((((size_t)(p * 16 + ks) * 8 + t8) * 2 + 0) * 64 + jl) * 8;
    *(bf16x8*)(wfrag + base)       = hi;
    *(bf16x8*)(wfrag + base + 512) = lo;      // c=1 block is +64 lanes * 8 shorts
}

// ---------------- main kernel
__global__ __launch_bounds__(256, 2)
void ada_mfma5(const float* __restrict__ x, const float* __restrict__ W,
               const float* __restrict__ bias, const float* __restrict__ alphas,
               const unsigned short* __restrict__ wfrag,
               float* __restrict__ out) {
    __shared__ unsigned short wbuf[2][8192];   // 2 x 16 KB W-fragment k-step buffers
    __shared__ int   se[WSLOTS];
    __shared__ float st[WSLOTS];
    __shared__ float sb[WSLOTS];
    __shared__ int   wcnt[4];

    const int tid = threadIdx.x;
    const int n0  = blockIdx.x * BM;

    // ---- compaction of active estimators (deterministic ballot prefix-sum)
    se[tid] = 0; st[tid] = 0.0f; sb[tid] = 0.0f;
    __syncthreads();
    const float t = truncf(alphas[tid]);
    const bool flag = (t != 0.0f);
    const unsigned long long m64 = __ballot(flag);
    const int lane = tid & 63, wv = tid >> 6;
    if (lane == 0) wcnt[wv] = __popcll(m64);
    __syncthreads();
    int off = 0;
    #pragma unroll
    for (int w = 0; w < 4; ++w) if (w < wv) off += wcnt[w];
    const int M = wcnt[0] + wcnt[1] + wcnt[2] + wcnt[3];
    if (flag) {
        const int slot = off + __popcll(m64 & ((1ull << lane) - 1ull));
        se[slot] = tid; st[slot] = t; sb[slot] = bias[tid];
    }
    __syncthreads();

    // ---- ids
    const int quad = (tid >> 4) & 3;
    const int l15  = tid & 15;
    const int rw   = wv * 32;            // wave's row base within block

    const float* xp0 = x + (size_t)(n0 + rw + l15) * F_DIM + quad * 8;
    const float* xp1 = xp0 + (size_t)16 * F_DIM;

    int part[2][4];
    #pragma unroll
    for (int mt = 0; mt < 2; ++mt)
        #pragma unroll
        for (int r = 0; r < 4; ++r) part[mt][r] = 0;

    for (int cb = 0; cb < M; cb += 128) {
        const unsigned short* wsp = wfrag + (size_t)(cb >> 7) * KSTEPS * 8192;

        f32x4 acc[2][NT];
        #pragma unroll
        for (int mt = 0; mt < 2; ++mt)
            #pragma unroll
            for (int nt = 0; nt < NT; ++nt)
                acc[mt][nt] = (f32x4){0.0f, 0.0f, 0.0f, 0.0f};

        // prologue: stage W k-step 0 into buf0 (DMA), prefetch x k-step 0
        {
            const unsigned short* gs = wsp + wv * 2048 + lane * 8;
            unsigned short* lb = &wbuf[0][wv * 2048];
            #pragma unroll
            for (int i = 0; i < 4; ++i)
                __builtin_amdgcn_global_load_lds(
                    (const __attribute__((address_space(1))) void*)(gs + i * 512),
                    (__attribute__((address_space(3))) void*)(lb + i * 512),
                    16, 0, 0);
        }
        f32x4 xn0 = *(const f32x4*)(xp0);
        f32x4 xn1 = *(const f32x4*)(xp0 + 4);
        f32x4 xn2 = *(const f32x4*)(xp1);
        f32x4 xn3 = *(const f32x4*)(xp1 + 4);
        __syncthreads();   // stage(0) complete (vmcnt drain covers x too)

        #pragma unroll
        for (int ks = 0; ks < KSTEPS; ++ks) {
            const int cur = ks & 1;

            // convert this step's x (consumes the prefetch registers)
            bf16x8 ah0, al0, ah1, al1;
            cvt8(xn0, xn1, ah0, al0);
            cvt8(xn2, xn3, ah1, al1);

            // issue next k-step's W stage (DMA into other buffer) + x prefetch
            if (ks + 1 < KSTEPS) {
                const unsigned short* gs = wsp + (size_t)(ks + 1) * 8192 + wv * 2048 + lane * 8;
                unsigned short* lb = &wbuf[cur ^ 1][wv * 2048];
                #pragma unroll
                for (int i = 0; i < 4; ++i)
                    __builtin_amdgcn_global_load_lds(
                        (const __attribute__((address_space(1))) void*)(gs + i * 512),
                        (__attribute__((address_space(3))) void*)(lb + i * 512),
                        16, 0, 0);
                const int kf = (ks + 1) * BK;
                xn0 = *(const f32x4*)(xp0 + kf);
                xn1 = *(const f32x4*)(xp0 + kf + 4);
                xn2 = *(const f32x4*)(xp1 + kf);
                xn3 = *(const f32x4*)(xp1 + kf + 4);
            }

            // 16 ds_read_b128 + 48 MFMAs from LDS buffer `cur`
            const unsigned short* wb = wbuf[cur];
            #pragma unroll
            for (int nt = 0; nt < NT; ++nt) {
                const bf16x8 bh = *(const bf16x8*)&wb[(nt * 2 + 0) * 512 + lane * 8];
                const bf16x8 bl = *(const bf16x8*)&wb[(nt * 2 + 1) * 512 + lane * 8];
                acc[0][nt] = __builtin_amdgcn_mfma_f32_16x16x32_bf16(ah0, bh, acc[0][nt], 0, 0, 0);
                acc[1][nt] = __builtin_amdgcn_mfma_f32_16x16x32_bf16(ah1, bh, acc[1][nt], 0, 0, 0);
                acc[0][nt] = __builtin_amdgcn_mfma_f32_16x16x32_bf16(al0, bh, acc[0][nt], 0, 0, 0);
                acc[1][nt] = __builtin_amdgcn_mfma_f32_16x16x32_bf16(al1, bh, acc[1][nt], 0, 0, 0);
                acc[0][nt] = __builtin_amdgcn_mfma_f32_16x16x32_bf16(ah0, bl, acc[0][nt], 0, 0, 0);
                acc[1][nt] = __builtin_amdgcn_mfma_f32_16x16x32_bf16(ah1, bl, acc[1][nt], 0, 0, 0);
            }

            __syncthreads();   // next buf staged + cur ds_reads done
        }

        // ---- epilogue phase 1 (call-free): fold acc into votes + masks.
        // bit b = nt*8 + mt*4 + r. acc is DEAD after this loop.
        unsigned long long bmask = 0ull, pmask = 0ull;
        #pragma unroll
        for (int nt = 0; nt < NT; ++nt) {
            const int col = cb + nt * 16 + l15;
            const float tv = st[col];
            const float bv = sb[col];
            const int it = (int)tv;
            #pragma unroll
            for (int mt = 0; mt < 2; ++mt) {
                #pragma unroll
                for (int r = 0; r < 4; ++r) {
                    const float logit = acc[mt][nt][r] + bv;
                    const bool pred = (logit > 0.0f);
                    if (tv != 0.0f) {
                        if (pred) part[mt][r] += it;
                        const unsigned long long bit = 1ull << (nt * 8 + mt * 4 + r);
                        if (fabsf(logit) < TAU) {
                            bmask |= bit;
                            if (pred) pmask |= bit;
                        }
                    }
                }
            }
        }

        // ---- epilogue phase 2 (rare, ~4% of threads): exact re-decide.
        // Static part[][] indexing; only scalars live across the call.
        if (bmask) {
            #pragma unroll
            for (int mt = 0; mt < 2; ++mt) {
                #pragma unroll
                for (int r = 0; r < 4; ++r) {
                    unsigned long long sel =
                        bmask & (0x0101010101010101ull << (mt * 4 + r));
                    while (sel) {
                        const int b = __builtin_ctzll(sel);
                        sel &= sel - 1;
                        const int nt  = b >> 3;
                        const int col = cb + nt * 16 + l15;
                        const int row = rw + mt * 16 + quad * 4 + r;
                        const bool q = exact_pred(x + (size_t)(n0 + row) * F_DIM,
                                                  W + (size_t)se[col] * F_DIM,
                                                  sb[col]);
                        const bool p = (pmask >> b) & 1ull;
                        if (q != p) {
                            const int it = (int)st[col];
                            part[mt][r] += q ? it : -it;
                        }
                    }
                }
            }
        }
    }

    // ---- reduce the 16 col-lanes of each quad, then store 4 consecutive rows
    #pragma unroll
    for (int mt = 0; mt < 2; ++mt) {
        #pragma unroll
        for (int r = 0; r < 4; ++r) {
            int v = part[mt][r];
            v += __shfl_xor(v, 1);
            v += __shfl_xor(v, 2);
            v += __shfl_xor(v, 4);
            v += __shfl_xor(v, 8);
            part[mt][r] = v;
        }
    }
    if (l15 == 0) {
        #pragma unroll
        for (int mt = 0; mt < 2; ++mt) {
            float4 o;
            o.x = (part[mt][0] > 0) ? 1.0f : (part[mt][0] < 0 ? -1.0f : 0.0f);
            o.y = (part[mt][1] > 0) ? 1.0f : (part[mt][1] < 0 ? -1.0f : 0.0f);
            o.z = (part[mt][2] > 0) ? 1.0f : (part[mt][2] < 0 ? -1.0f : 0.0f);
            o.w = (part[mt][3] > 0) ? 1.0f : (part[mt][3] < 0 ? -1.0f : 0.0f);
            *(float4*)(out + n0 + rw + mt * 16 + quad * 4) = o;
        }
    }
}

extern "C" void kernel_launch(void* const* d_in, const int* in_sizes, int n_in,
                              void* d_out, int out_size, void* d_ws, size_t ws_size,
                              hipStream_t stream) {
    const float* x      = (const float*)d_in[0];   // [N, 512]
    const float* W      = (const float*)d_in[1];   // [256, 512]
    const float* bias   = (const float*)d_in[2];   // [256]
    const float* alphas = (const float*)d_in[3];   // [256]
    float* out = (float*)d_out;                    // [N]

    const int n = in_sizes[0] / F_DIM;             // 131072
    const int nblocks = n / BM;                    // 1024

    // ws: W fragments bf16 hi/lo, fragment-linear, 2 passes x 16 ksteps x 16 KB = 512 KB
    unsigned short* wfrag = (unsigned short*)d_ws;

    ada_prep<<<dim3(64), dim3(256), 0, stream>>>(W, alphas, wfrag);
    ada_mfma5<<<dim3(nblocks), dim3(256), 0, stream>>>(x, W, bias, alphas, wfrag, out);
}

// Round 5
// 508.424 us; speedup vs baseline: 1.2238x; 1.0614x over previous
//
#include <hip/hip_runtime.h>
#include <math.h>

// AdaBoost fused inference, v6: call-free main kernel + deferred exact fixup.
//   logits = x @ W^T + b   [N=131072, E=256], F=512; pred = (logit > 0)
//   out = sign( sum_e trunc(alpha_e) * pred_e ), only cols with trunc(alpha)!=0 matter.
//
// v5 post-mortem: WRITE_SIZE stayed ~137 MB, VGPR pinned at 128, dur 290 us
// with all pipes idle. The embedded noinline exact_pred call is the common
// factor across every slow version: it imposes call-ABI/scratch on the whole
// kernel AND runs a divergent 512-iter fp64 gather loop in ~83% of waves
// (P(>=1 borderline per wave) with ~81 active estimators).
// v6 removes the call from the hot kernel entirely:
//   ada_prep  - compact estimators, pre-split W to bf16 hi/lo fragment-linear
//               (as v5) + zero the borderline-record counter.
//   ada_mfma6 - v5's k-loop (LDS DMA double-buffer, 1 barrier/kstep) with a
//               100% call-free epilogue: integer votes -> ws, borderline
//               records appended to a global list (atomicAdd; ~7K expected).
//   ada_fix   - one thread per record: exact fp64 dot, atomically corrects
//               votes[row] on approx/exact disagreement.
//   ada_sign  - out[i] = sign(votes[i]).
// Stream order gives cross-kernel visibility; integer atomics are
// order-independent -> bit-identical result.

#define F_DIM  512
#define BM     128      // rows per block (4 waves x 32 rows)
#define BK     32       // k per MFMA step
#define KSTEPS 16       // F_DIM / BK
#define NT     8        // 16-col MFMA tiles per pass (always 128 cols)
#define WSLOTS 256
#define TAU    1e-3f
#define RECCAP 65536

typedef float f32x4  __attribute__((ext_vector_type(4)));
typedef short bf16x8 __attribute__((ext_vector_type(8)));

__device__ inline unsigned short bf16_rne(float v) {
    unsigned u = __float_as_uint(v);
    u += 0x7FFFu + ((u >> 16) & 1u);
    return (unsigned short)(u >> 16);
}
__device__ inline float bf16_to_f32(unsigned short h) {
    return __uint_as_float(((unsigned)h) << 16);
}

// split 8 floats (a[0..3], b[0..3]) into bf16 hi/lo fragments
__device__ inline void cvt8(const f32x4 a, const f32x4 b, bf16x8& hi, bf16x8& lo) {
    #pragma unroll
    for (int j = 0; j < 4; ++j) {
        const float v0 = a[j], v1 = b[j];
        const unsigned short h0 = bf16_rne(v0);
        const unsigned short h1 = bf16_rne(v1);
        hi[j]     = (short)h0;
        hi[j + 4] = (short)h1;
        lo[j]     = (short)bf16_rne(v0 - bf16_to_f32(h0));
        lo[j + 4] = (short)bf16_rne(v1 - bf16_to_f32(h1));
    }
}

// ---------------- pre-kernel: compact active estimators, split W -> bf16 hi/lo
// fragments in ws, fragment-LINEAR layout (stage-able by global_load_lds):
//   wfrag[((((p*16 + ks)*8 + t8)*2 + c)*64 + lane)*8 + j]
//     = bf16_c( W[ se[p*128 + t8*16 + (lane&15)] ][ ks*32 + (lane>>4)*8 + j ] )
// One (p,ks) block = 16 KB, contiguous.
__global__ __launch_bounds__(256)
void ada_prep(const float* __restrict__ W, const float* __restrict__ alphas,
              unsigned short* __restrict__ wfrag, int* __restrict__ cnt) {
    __shared__ int se[WSLOTS];
    __shared__ int wcnt[4];
    const int tid = threadIdx.x;

    if (blockIdx.x == 0 && tid == 0) *cnt = 0;   // reset record counter

    se[tid] = 0;
    __syncthreads();
    const float t = truncf(alphas[tid]);
    const bool flag = (t != 0.0f);
    const unsigned long long m64 = __ballot(flag);
    const int lane = tid & 63, wvi = tid >> 6;
    if (lane == 0) wcnt[wvi] = __popcll(m64);
    __syncthreads();
    int off = 0;
    #pragma unroll
    for (int w = 0; w < 4; ++w) if (w < wvi) off += wcnt[w];
    if (flag) se[off + __popcll(m64 & ((1ull << lane) - 1ull))] = tid;
    __syncthreads();

    // 16384 jobs = 64 blocks x 256 threads; one job = one 8-elem lane fragment
    const int job = blockIdx.x * 256 + tid;
    const int jl  = job & 63;            // dest lane
    const int t8  = (job >> 6) & 7;      // tile within pass
    const int ks  = (job >> 9) & 15;     // k-step
    const int p   = (job >> 13) & 1;     // pass
    const int col = p * 128 + t8 * 16 + (jl & 15);
    const int k   = ks * 32 + (jl >> 4) * 8;

    const float* src = W + (size_t)se[col] * F_DIM + k;
    const f32x4 a = *(const f32x4*)(src);
    const f32x4 b = *(const f32x4*)(src + 4);
    bf16x8 hi, lo;
    cvt8(a, b, hi, lo);

    const size_t base = ((((size_t)(p * 16 + ks) * 8 + t8) * 2 + 0) * 64 + jl) * 8;
    *(bf16x8*)(wfrag + base)       = hi;
    *(bf16x8*)(wfrag + base + 512) = lo;      // c=1 block is +64 lanes * 8 shorts
}

// ---------------- main kernel: NO calls, NO fp64, votes + borderline records
__global__ __launch_bounds__(256, 2)
void ada_mfma6(const float* __restrict__ x,
               const float* __restrict__ bias, const float* __restrict__ alphas,
               const unsigned short* __restrict__ wfrag,
               int* __restrict__ votes, int* __restrict__ cnt,
               int* __restrict__ rec) {
    __shared__ unsigned short wbuf[2][8192];   // 2 x 16 KB W-fragment k-step buffers
    __shared__ int   se[WSLOTS];
    __shared__ float st[WSLOTS];
    __shared__ float sb[WSLOTS];
    __shared__ int   wcnt[4];

    const int tid = threadIdx.x;
    const int n0  = blockIdx.x * BM;

    // ---- compaction of active estimators (deterministic ballot prefix-sum)
    se[tid] = 0; st[tid] = 0.0f; sb[tid] = 0.0f;
    __syncthreads();
    const float t = truncf(alphas[tid]);
    const bool flag = (t != 0.0f);
    const unsigned long long m64 = __ballot(flag);
    const int lane = tid & 63, wv = tid >> 6;
    if (lane == 0) wcnt[wv] = __popcll(m64);
    __syncthreads();
    int off = 0;
    #pragma unroll
    for (int w = 0; w < 4; ++w) if (w < wv) off += wcnt[w];
    const int M = wcnt[0] + wcnt[1] + wcnt[2] + wcnt[3];
    if (flag) {
        const int slot = off + __popcll(m64 & ((1ull << lane) - 1ull));
        se[slot] = tid; st[slot] = t; sb[slot] = bias[tid];
    }
    __syncthreads();

    // ---- ids
    const int quad = (tid >> 4) & 3;
    const int l15  = tid & 15;
    const int rw   = wv * 32;            // wave's row base within block

    const float* xp0 = x + (size_t)(n0 + rw + l15) * F_DIM + quad * 8;
    const float* xp1 = xp0 + (size_t)16 * F_DIM;

    int part[2][4];
    #pragma unroll
    for (int mt = 0; mt < 2; ++mt)
        #pragma unroll
        for (int r = 0; r < 4; ++r) part[mt][r] = 0;

    for (int cb = 0; cb < M; cb += 128) {
        const unsigned short* wsp = wfrag + (size_t)(cb >> 7) * KSTEPS * 8192;

        f32x4 acc[2][NT];
        #pragma unroll
        for (int mt = 0; mt < 2; ++mt)
            #pragma unroll
            for (int nt = 0; nt < NT; ++nt)
                acc[mt][nt] = (f32x4){0.0f, 0.0f, 0.0f, 0.0f};

        // prologue: stage W k-step 0 into buf0 (DMA), prefetch x k-step 0
        {
            const unsigned short* gs = wsp + wv * 2048 + lane * 8;
            unsigned short* lb = &wbuf[0][wv * 2048];
            #pragma unroll
            for (int i = 0; i < 4; ++i)
                __builtin_amdgcn_global_load_lds(
                    (const __attribute__((address_space(1))) void*)(gs + i * 512),
                    (__attribute__((address_space(3))) void*)(lb + i * 512),
                    16, 0, 0);
        }
        f32x4 xn0 = *(const f32x4*)(xp0);
        f32x4 xn1 = *(const f32x4*)(xp0 + 4);
        f32x4 xn2 = *(const f32x4*)(xp1);
        f32x4 xn3 = *(const f32x4*)(xp1 + 4);
        __syncthreads();   // stage(0) complete

        #pragma unroll
        for (int ks = 0; ks < KSTEPS; ++ks) {
            const int cur = ks & 1;

            // convert this step's x (consumes the prefetch registers)
            bf16x8 ah0, al0, ah1, al1;
            cvt8(xn0, xn1, ah0, al0);
            cvt8(xn2, xn3, ah1, al1);

            // issue next k-step's W stage (DMA into other buffer) + x prefetch
            if (ks + 1 < KSTEPS) {
                const unsigned short* gs = wsp + (size_t)(ks + 1) * 8192 + wv * 2048 + lane * 8;
                unsigned short* lb = &wbuf[cur ^ 1][wv * 2048];
                #pragma unroll
                for (int i = 0; i < 4; ++i)
                    __builtin_amdgcn_global_load_lds(
                        (const __attribute__((address_space(1))) void*)(gs + i * 512),
                        (__attribute__((address_space(3))) void*)(lb + i * 512),
                        16, 0, 0);
                const int kf = (ks + 1) * BK;
                xn0 = *(const f32x4*)(xp0 + kf);
                xn1 = *(const f32x4*)(xp0 + kf + 4);
                xn2 = *(const f32x4*)(xp1 + kf);
                xn3 = *(const f32x4*)(xp1 + kf + 4);
            }

            // 16 ds_read_b128 + 48 MFMAs from LDS buffer `cur`
            const unsigned short* wb = wbuf[cur];
            #pragma unroll
            for (int nt = 0; nt < NT; ++nt) {
                const bf16x8 bh = *(const bf16x8*)&wb[(nt * 2 + 0) * 512 + lane * 8];
                const bf16x8 bl = *(const bf16x8*)&wb[(nt * 2 + 1) * 512 + lane * 8];
                acc[0][nt] = __builtin_amdgcn_mfma_f32_16x16x32_bf16(ah0, bh, acc[0][nt], 0, 0, 0);
                acc[1][nt] = __builtin_amdgcn_mfma_f32_16x16x32_bf16(ah1, bh, acc[1][nt], 0, 0, 0);
                acc[0][nt] = __builtin_amdgcn_mfma_f32_16x16x32_bf16(al0, bh, acc[0][nt], 0, 0, 0);
                acc[1][nt] = __builtin_amdgcn_mfma_f32_16x16x32_bf16(al1, bh, acc[1][nt], 0, 0, 0);
                acc[0][nt] = __builtin_amdgcn_mfma_f32_16x16x32_bf16(ah0, bl, acc[0][nt], 0, 0, 0);
                acc[1][nt] = __builtin_amdgcn_mfma_f32_16x16x32_bf16(ah1, bl, acc[1][nt], 0, 0, 0);
            }

            __syncthreads();   // next buf staged + cur ds_reads done
        }

        // ---- epilogue (call-free): votes + borderline record append
        #pragma unroll
        for (int nt = 0; nt < NT; ++nt) {
            const int col = cb + nt * 16 + l15;
            const float tv = st[col];
            const float bv = sb[col];
            const int it = (int)tv;
            #pragma unroll
            for (int mt = 0; mt < 2; ++mt) {
                #pragma unroll
                for (int r = 0; r < 4; ++r) {
                    const float logit = acc[mt][nt][r] + bv;
                    const bool pred = (logit > 0.0f);
                    if (tv != 0.0f) {
                        if (pred) part[mt][r] += it;
                        if (fabsf(logit) < TAU) {
                            const int row = n0 + rw + mt * 16 + quad * 4 + r;
                            const int idx = atomicAdd(cnt, 1);
                            if (idx < RECCAP)
                                rec[idx] = (row << 9) | (se[col] << 1) | (pred ? 1 : 0);
                        }
                    }
                }
            }
        }
    }

    // ---- reduce the 16 col-lanes of each quad, store 4 consecutive int votes
    #pragma unroll
    for (int mt = 0; mt < 2; ++mt) {
        #pragma unroll
        for (int r = 0; r < 4; ++r) {
            int v = part[mt][r];
            v += __shfl_xor(v, 1);
            v += __shfl_xor(v, 2);
            v += __shfl_xor(v, 4);
            v += __shfl_xor(v, 8);
            part[mt][r] = v;
        }
    }
    if (l15 == 0) {
        #pragma unroll
        for (int mt = 0; mt < 2; ++mt) {
            int4 o;
            o.x = part[mt][0]; o.y = part[mt][1];
            o.z = part[mt][2]; o.w = part[mt][3];
            *(int4*)(votes + n0 + rw + mt * 16 + quad * 4) = o;
        }
    }
}

// ---------------- fixup kernel: exact fp64 re-decide for borderline records
__global__ __launch_bounds__(256)
void ada_fix(const float* __restrict__ x, const float* __restrict__ W,
             const float* __restrict__ bias, const float* __restrict__ alphas,
             int* __restrict__ votes, const int* __restrict__ cnt,
             const int* __restrict__ rec) {
    int n = *cnt;
    if (n > RECCAP) n = RECCAP;
    const int stride = gridDim.x * blockDim.x;
    for (int i = blockIdx.x * blockDim.x + threadIdx.x; i < n; i += stride) {
        const int r    = rec[i];
        const int row  = r >> 9;
        const int e    = (r >> 1) & 255;
        const int pred = r & 1;

        const float* xr = x + (size_t)row * F_DIM;
        const float* wr = W + (size_t)e * F_DIM;
        double s0 = 0.0, s1 = 0.0, s2 = 0.0, s3 = 0.0;
        for (int k = 0; k < F_DIM; k += 4) {
            s0 = fma((double)xr[k + 0], (double)wr[k + 0], s0);
            s1 = fma((double)xr[k + 1], (double)wr[k + 1], s1);
            s2 = fma((double)xr[k + 2], (double)wr[k + 2], s2);
            s3 = fma((double)xr[k + 3], (double)wr[k + 3], s3);
        }
        const double s = ((s0 + s1) + (s2 + s3)) + (double)bias[e];
        const int q = (s > 0.0) ? 1 : 0;
        if (q != pred) {
            const int it = (int)truncf(alphas[e]);
            atomicAdd(&votes[row], q ? it : -it);
        }
    }
}

// ---------------- sign kernel
__global__ __launch_bounds__(256)
void ada_sign(const int* __restrict__ votes, float* __restrict__ out, int n4) {
    const int i = blockIdx.x * blockDim.x + threadIdx.x;
    if (i < n4) {
        const int4 v = *(const int4*)(votes + i * 4);
        float4 o;
        o.x = (v.x > 0) ? 1.0f : (v.x < 0 ? -1.0f : 0.0f);
        o.y = (v.y > 0) ? 1.0f : (v.y < 0 ? -1.0f : 0.0f);
        o.z = (v.z > 0) ? 1.0f : (v.z < 0 ? -1.0f : 0.0f);
        o.w = (v.w > 0) ? 1.0f : (v.w < 0 ? -1.0f : 0.0f);
        *(float4*)(out + i * 4) = o;
    }
}

extern "C" void kernel_launch(void* const* d_in, const int* in_sizes, int n_in,
                              void* d_out, int out_size, void* d_ws, size_t ws_size,
                              hipStream_t stream) {
    const float* x      = (const float*)d_in[0];   // [N, 512]
    const float* W      = (const float*)d_in[1];   // [256, 512]
    const float* bias   = (const float*)d_in[2];   // [256]
    const float* alphas = (const float*)d_in[3];   // [256]
    float* out = (float*)d_out;                    // [N]

    const int n = in_sizes[0] / F_DIM;             // 131072
    const int nblocks = n / BM;                    // 1024

    // ws layout:
    //   [0, 512K)        wfrag: W bf16 hi/lo fragments (2 passes x 16 ksteps x 16 KB)
    //   [512K, 1M)       votes: int[N]
    //   [1M, 1M+256)     cnt
    //   [1M+256, +256K)  rec: int[RECCAP]
    char* wsb = (char*)d_ws;
    unsigned short* wfrag = (unsigned short*)wsb;
    int* votes = (int*)(wsb + (512u << 10));
    int* cnt   = (int*)(wsb + (1024u << 10));
    int* rec   = (int*)(wsb + (1024u << 10) + 256);

    ada_prep<<<dim3(64), dim3(256), 0, stream>>>(W, alphas, wfrag, cnt);
    ada_mfma6<<<dim3(nblocks), dim3(256), 0, stream>>>(x, bias, alphas, wfrag, votes, cnt, rec);
    ada_fix<<<dim3(32), dim3(256), 0, stream>>>(x, W, bias, alphas, votes, cnt, rec);
    ada_sign<<<dim3(n / 1024), dim3(256), 0, stream>>>(votes, out, n / 4);
}